// Round 3
// baseline (520.844 us; speedup 1.0000x reference)
//
#include <hip/hip_runtime.h>

// Shape fixed by the reference: data/mask [B,T,D] float32.
#define BB 8
#define TT 4096
#define DD 1024
#define D4 256            // DD/4 float4 columns
#define LL 16             // chunk (tile) length along T
#define CC 256            // TT/LL tiles per (b) chain
#define NTILE (BB * CC)   // 2048 tiles total

// Single-pass forward-fill with decoupled lookback.
// Block = 256 threads = one tile (b, c): rows [c*LL, (c+1)*LL) x all 1024 d.
// Thread d4 owns one float4 column of the tile.
__global__ __launch_bounds__(256) void ff_onepass(
    const float4* __restrict__ data, const float4* __restrict__ mask,
    float4* __restrict__ outf, float4* __restrict__ outm,
    int* __restrict__ ticket, int* __restrict__ status,
    float4* __restrict__ pV, unsigned char* __restrict__ pF) {
  // Deadlock-safe tile assignment: earlier tickets -> smaller c.
  __shared__ int s_t;
  if (threadIdx.x == 0) s_t = atomicAdd(ticket, 1);
  __syncthreads();
  const int t = s_t;
  const int c = t >> 3;       // 0..255
  const int b = t & 7;        // 0..7
  const int d4 = threadIdx.x;
  const int tile = b * CC + c;

  // ---- pass 1: stream the tile once; fill with carry-in assumed FILL=0 ----
  float4 last = make_float4(0.f, 0.f, 0.f, 0.f);
  unsigned f = 0;                       // found nibble (4 scalar lanes)
  unsigned long long holes = 0ULL;      // per (row,lane) still-unfound bits
  const long rowbase = ((long)b * TT + (long)c * LL) * D4 + d4;
  long base = rowbase;
#pragma unroll 4
  for (int i = 0; i < LL; ++i, base += D4) {
    float4 m = mask[base];
    float4 v = data[base];
    outm[base] = m;                     // mask pass-through (output 1)
    if (m.x > 0.f) { last.x = v.x; f |= 1u; }
    if (m.y > 0.f) { last.y = v.y; f |= 2u; }
    if (m.z > 0.f) { last.z = v.z; f |= 4u; }
    if (m.w > 0.f) { last.w = v.w; f |= 8u; }
    holes |= (unsigned long long)((~f) & 0xFu) << (i * 4);
    outf[base] = last;                  // holes carry 0.0 for now
  }

  // ---- publish aggregate (no cross-tile dependency) ----
  const long pidx = (long)tile * 256 + d4;
  pV[pidx] = last;
  pF[pidx] = (unsigned char)f;
  __syncthreads();                      // drain all payload stores
  if (threadIdx.x == 0)
    __hip_atomic_store(&status[tile], 1, __ATOMIC_RELEASE,
                       __HIP_MEMORY_SCOPE_AGENT);

  // ---- lookback: resolve carry for lanes with holes (expected depth 1) ----
  // A lane has holes iff it has a hole at row 0 (holes are a prefix).
  unsigned need = (unsigned)(holes & 0xFull);
  float4 carry = make_float4(0.f, 0.f, 0.f, 0.f);
  if (c > 0 && need) {
    int p = c - 1;
    for (;;) {
      const int st = tile - (c - p);    // b*CC + p
      if (__hip_atomic_load(&status[st], __ATOMIC_ACQUIRE,
                            __HIP_MEMORY_SCOPE_AGENT) == 0) {
        do {
          __builtin_amdgcn_s_sleep(8);
        } while (__hip_atomic_load(&status[st], __ATOMIC_ACQUIRE,
                                   __HIP_MEMORY_SCOPE_AGENT) == 0);
      }
      const long q = (long)st * 256 + d4;
      float4 pv = pV[q];
      unsigned pf = (unsigned)pF[q];
      unsigned take = need & pf;
      if (take & 1) carry.x = pv.x;
      if (take & 2) carry.y = pv.y;
      if (take & 4) carry.z = pv.z;
      if (take & 8) carry.w = pv.w;
      need &= ~pf;
      if (!need || p == 0) break;       // p==0 with need left => carry=FILL=0
      --p;
    }
  }

  // ---- fixup: patch holes with carry (skip when carry == FILL = 0.0) ----
  if (holes) {
    float* of = (float*)outf;
    unsigned long long h = holes;
    long ebase = rowbase * 4;           // scalar index of (row, lane 0)
    for (; h; h >>= 4, ebase += (long)D4 * 4) {
      unsigned nib = (unsigned)(h & 0xFull);
      if ((nib & 1) && carry.x != 0.f) of[ebase + 0] = carry.x;
      if ((nib & 2) && carry.y != 0.f) of[ebase + 1] = carry.y;
      if ((nib & 4) && carry.z != 0.f) of[ebase + 2] = carry.z;
      if ((nib & 8) && carry.w != 0.f) of[ebase + 3] = carry.w;
    }
  }
}

// Fallback if workspace too small: one thread per (b, d4) full-column scan.
__global__ __launch_bounds__(256) void ff_naive(
    const float4* __restrict__ data, const float4* __restrict__ mask,
    float4* __restrict__ outf, float4* __restrict__ outm) {
  int tid = blockIdx.x * blockDim.x + threadIdx.x;
  if (tid >= BB * D4) return;
  int d4 = tid & (D4 - 1);
  int b = tid / D4;
  float4 last = make_float4(0.f, 0.f, 0.f, 0.f);
  long base = (long)b * TT * D4 + d4;
  for (int t = 0; t < TT; ++t, base += D4) {
    float4 m = mask[base];
    float4 v = data[base];
    last.x = (m.x > 0.f) ? v.x : last.x;
    last.y = (m.y > 0.f) ? v.y : last.y;
    last.z = (m.z > 0.f) ? v.z : last.z;
    last.w = (m.w > 0.f) ? v.w : last.w;
    outf[base] = last;
    outm[base] = m;
  }
}

extern "C" void kernel_launch(void* const* d_in, const int* in_sizes, int n_in,
                              void* d_out, int out_size, void* d_ws, size_t ws_size,
                              hipStream_t stream) {
  const float4* data = (const float4*)d_in[0];
  const float4* mask = (const float4*)d_in[1];
  const long N = (long)BB * TT * DD;
  float4* outf = (float4*)d_out;
  float4* outm = (float4*)((float*)d_out + N);

  // Workspace layout: [0,4) ticket | [512, 512+8K) status | pad |
  //                   [16K, 16K+8M) payloadV | payloadF 512K
  const size_t off_status = 512;
  const size_t off_pV = 16384;
  const size_t bytes_pV = (size_t)NTILE * 256 * sizeof(float4);  // 8 MiB
  const size_t off_pF = off_pV + bytes_pV;
  const size_t need = off_pF + (size_t)NTILE * 256;              // ~8.6 MiB

  if (ws_size >= need) {
    char* w = (char*)d_ws;
    int* ticket = (int*)w;
    int* status = (int*)(w + off_status);
    float4* pV = (float4*)(w + off_pV);
    unsigned char* pF = (unsigned char*)(w + off_pF);

    // Zero ticket + status each call (d_ws is not re-poisoned between replays).
    hipMemsetAsync(d_ws, 0, off_pV, stream);
    ff_onepass<<<NTILE, 256, 0, stream>>>(data, mask, outf, outm, ticket,
                                          status, pV, pF);
  } else {
    ff_naive<<<(BB * D4 + 255) / 256, 256, 0, stream>>>(data, mask, outf, outm);
  }
}

// Round 5
// 123.901 us; speedup vs baseline: 4.2037x; 4.2037x over previous
//
#include <hip/hip_runtime.h>

// Shape fixed by the reference: data/mask [B,T,D] float32.
#define BB 8
#define TT 4096
#define DD 1024
#define D4 256            // DD/4 float4 columns
#define LL 32             // chunk length along T
#define CC 128            // TT/LL chunks per (b, d4) column

typedef float f4 __attribute__((ext_vector_type(4)));  // nontemporal-friendly

// ---------------------------------------------------------------------------
// Kernel 1: fused chunk-aggregate + cross-chunk exclusive scan.
// Block = 256 threads = 128 chunks x 2 adjacent d4 columns of one b.
// Each thread backward-scans its chunk with early exit (~1.4 rows read at
// 10% missing), then an in-LDS Hillis-Steele scan produces the exclusive
// carry-in per chunk. "No valid yet" == 0.0 == FILL_VALUE, so cin is
// flag-free. Grid = B * D4/2 = 1024 blocks. Total traffic ~10 MB.
// ---------------------------------------------------------------------------
__global__ __launch_bounds__(256) void ff_scan(
    const f4* __restrict__ data, const f4* __restrict__ mask,
    f4* __restrict__ cin) {
  const int bx = blockIdx.x;                 // b*(D4/2) + colpair
  const int b = bx >> 7;
  const int c = threadIdx.x >> 1;            // chunk 0..127
  const int j = threadIdx.x & 1;             // column-in-pair
  const int d4 = ((bx & 127) << 1) | j;

  // chunk aggregate (last valid per scalar lane, backward early-exit)
  f4 val = {0.f, 0.f, 0.f, 0.f};
  int f = 0;
  long base = ((long)b * TT + (long)c * LL + (LL - 1)) * D4 + d4;
  for (int i = LL - 1; i >= 0 && f != 0xF; --i, base -= D4) {
    f4 m = mask[base];
    f4 v = data[base];
    if (!(f & 1) && m.x > 0.f) { val.x = v.x; f |= 1; }
    if (!(f & 2) && m.y > 0.f) { val.y = v.y; f |= 2; }
    if (!(f & 4) && m.z > 0.f) { val.z = v.z; f |= 4; }
    if (!(f & 8) && m.w > 0.f) { val.w = v.w; f |= 8; }
  }

  __shared__ f4 sV[CC][2];
  __shared__ int sF[CC][2];
  sV[c][j] = val;
  sF[c][j] = f;
  __syncthreads();

  // inclusive Hillis-Steele over chunks (combine: current overrides pred
  // where current has found; flags OR)
  for (int s = 1; s < CC; s <<= 1) {
    f4 pv = {0.f, 0.f, 0.f, 0.f};
    int pf = 0;
    if (c >= s) { pv = sV[c - s][j]; pf = sF[c - s][j]; }
    __syncthreads();
    if (c >= s) {
      f4 cv = sV[c][j];
      int cf = sF[c][j];
      if (!(cf & 1)) cv.x = pv.x;
      if (!(cf & 2)) cv.y = pv.y;
      if (!(cf & 4)) cv.z = pv.z;
      if (!(cf & 8)) cv.w = pv.w;
      sV[c][j] = cv;
      sF[c][j] = cf | pf;
    }
    __syncthreads();
  }

  // exclusive = inclusive[c-1]; c==0 -> FILL (0.0)
  f4 ex = {0.f, 0.f, 0.f, 0.f};
  if (c > 0) ex = sV[c - 1][j];
  cin[((long)b * CC + c) * D4 + d4] = ex;
}

// ---------------------------------------------------------------------------
// Kernel 2 (dominant): streaming forward fill from carry-in. Reads data+mask
// once, writes filled+mask once — all nontemporal (no reuse; keep L2 clean).
// Grid = B*CC*D4/256 = 1024 blocks, 4/CU.
// ---------------------------------------------------------------------------
__global__ __launch_bounds__(256) void ff_apply(
    const f4* __restrict__ data, const f4* __restrict__ mask,
    const f4* __restrict__ cin, f4* __restrict__ outf,
    f4* __restrict__ outm) {
  const int tid = blockIdx.x * 256 + threadIdx.x;  // B*CC*D4 = 262144
  f4 last = cin[tid];
  long base = (long)(tid >> 8) * (LL * D4) + (tid & 255);
#pragma unroll 4
  for (int i = 0; i < LL; ++i, base += D4) {
    f4 m = __builtin_nontemporal_load(&mask[base]);
    f4 v = __builtin_nontemporal_load(&data[base]);
    last.x = (m.x > 0.f) ? v.x : last.x;
    last.y = (m.y > 0.f) ? v.y : last.y;
    last.z = (m.z > 0.f) ? v.z : last.z;
    last.w = (m.w > 0.f) ? v.w : last.w;
    __builtin_nontemporal_store(last, &outf[base]);
    __builtin_nontemporal_store(m, &outm[base]);
  }
}

// ---------------------------------------------------------------------------
// Fallback if workspace too small: one thread per (b, d4) full-column scan.
// ---------------------------------------------------------------------------
__global__ __launch_bounds__(256) void ff_naive(
    const f4* __restrict__ data, const f4* __restrict__ mask,
    f4* __restrict__ outf, f4* __restrict__ outm) {
  int tid = blockIdx.x * blockDim.x + threadIdx.x;
  if (tid >= BB * D4) return;
  int d4 = tid & (D4 - 1);
  int b = tid / D4;
  f4 last = {0.f, 0.f, 0.f, 0.f};
  long base = (long)b * TT * D4 + d4;
  for (int t = 0; t < TT; ++t, base += D4) {
    f4 m = mask[base];
    f4 v = data[base];
    last.x = (m.x > 0.f) ? v.x : last.x;
    last.y = (m.y > 0.f) ? v.y : last.y;
    last.z = (m.z > 0.f) ? v.z : last.z;
    last.w = (m.w > 0.f) ? v.w : last.w;
    outf[base] = last;
    outm[base] = m;
  }
}

extern "C" void kernel_launch(void* const* d_in, const int* in_sizes, int n_in,
                              void* d_out, int out_size, void* d_ws, size_t ws_size,
                              hipStream_t stream) {
  const f4* data = (const f4*)d_in[0];
  const f4* mask = (const f4*)d_in[1];
  const long N = (long)BB * TT * DD;
  f4* outf = (f4*)d_out;
  f4* outm = (f4*)((float*)d_out + N);

  const size_t nCin = (size_t)BB * CC * D4;          // 262144 float4 = 4 MiB
  const size_t need = nCin * sizeof(f4);

  if (ws_size >= need) {
    f4* cin = (f4*)d_ws;
    ff_scan<<<BB * (D4 / 2), 256, 0, stream>>>(data, mask, cin);
    ff_apply<<<(int)(nCin / 256), 256, 0, stream>>>(data, mask, cin, outf,
                                                    outm);
  } else {
    ff_naive<<<(BB * D4 + 255) / 256, 256, 0, stream>>>(data, mask, outf, outm);
  }
}

// Round 6
// 109.263 us; speedup vs baseline: 4.7669x; 1.1340x over previous
//
#include <hip/hip_runtime.h>

// Shape fixed by the reference: data/mask [B,T,D] float32.
#define BB 8
#define TT 4096
#define DD 1024
#define D4 256            // DD/4 float4 columns
#define LL 32             // rows per block along T
#define CC 128            // TT/LL chunks per batch

typedef float f4 __attribute__((ext_vector_type(4)));

// ---------------------------------------------------------------------------
// Single fused kernel. Block = one (b, chunk): rows [c*LL, (c+1)*LL) x all
// 1024 d. Thread d4 owns one float4 column.
//
// Prologue: carry-in is computed by walking BACKWARD from row c*LL-1 in the
// raw input with per-scalar early exit (expected ~3.3 rows per wave at 10%
// missing => ~27 MB extra reads total). Pure input reads: no workspace, no
// inter-block ordering assumptions, no scan dispatch, no launch gap.
//
// Body: streaming forward fill; nontemporal loads/stores (no reuse).
// ---------------------------------------------------------------------------
__global__ __launch_bounds__(256) void ff_fused(
    const f4* __restrict__ data, const f4* __restrict__ mask,
    f4* __restrict__ outf, f4* __restrict__ outm) {
  const int bc = blockIdx.x;        // b*CC + c
  const int c = bc & (CC - 1);
  const int d4 = threadIdx.x;

  // ---- prologue: backward early-exit walk for the carry-in ----
  f4 last = {0.f, 0.f, 0.f, 0.f};   // "no valid yet" == FILL_VALUE == 0.0
  int f = 0;
  {
    long r = (long)c * LL - 1;                   // within-b row (>=0 stays in b)
    long p = (long)bc * LL * D4 + d4 - D4;       // f4 index of (b, r, d4)
    for (; r >= 0 && f != 0xF; --r, p -= D4) {
      f4 m = mask[p];                            // cached loads (may hit L2)
      f4 v = data[p];
      if (!(f & 1) && m.x > 0.f) { last.x = v.x; f |= 1; }
      if (!(f & 2) && m.y > 0.f) { last.y = v.y; f |= 2; }
      if (!(f & 4) && m.z > 0.f) { last.z = v.z; f |= 4; }
      if (!(f & 8) && m.w > 0.f) { last.w = v.w; f |= 8; }
    }
  }

  // ---- body: streaming forward fill + mask pass-through ----
  long base = (long)bc * LL * D4 + d4;
#pragma unroll 4
  for (int i = 0; i < LL; ++i, base += D4) {
    f4 m = __builtin_nontemporal_load(&mask[base]);
    f4 v = __builtin_nontemporal_load(&data[base]);
    last.x = (m.x > 0.f) ? v.x : last.x;
    last.y = (m.y > 0.f) ? v.y : last.y;
    last.z = (m.z > 0.f) ? v.z : last.z;
    last.w = (m.w > 0.f) ? v.w : last.w;
    __builtin_nontemporal_store(last, &outf[base]);
    __builtin_nontemporal_store(m, &outm[base]);
  }
}

extern "C" void kernel_launch(void* const* d_in, const int* in_sizes, int n_in,
                              void* d_out, int out_size, void* d_ws, size_t ws_size,
                              hipStream_t stream) {
  const f4* data = (const f4*)d_in[0];
  const f4* mask = (const f4*)d_in[1];
  const long N = (long)BB * TT * DD;
  f4* outf = (f4*)d_out;
  f4* outm = (f4*)((float*)d_out + N);

  ff_fused<<<BB * CC, 256, 0, stream>>>(data, mask, outf, outm);
}

// Round 7
// 87.862 us; speedup vs baseline: 5.9280x; 1.2436x over previous
//
#include <hip/hip_runtime.h>

// Shape fixed by the reference: data/mask [B,T,D] float32.
#define BB 8
#define TT 4096
#define DD 1024
#define D4 256            // DD/4 float4 columns
#define LL 32             // rows per block along T
#define CC 128            // TT/LL chunks per batch

typedef float f4 __attribute__((ext_vector_type(4)));

// ---------------------------------------------------------------------------
// Single fused kernel. Block = one (b, chunk): rows [c*LL, (c+1)*LL) x all
// 1024 d. Thread d4 owns one float4 column.
//
// Prologue: carry-in via BACKWARD walk over raw input, batched 4 rows per
// step with unconditional loads -> typically ONE memory round-trip (instead
// of a 3-4 deep dependent chain). P(a lane needs >4 rows) ~ 4e-4.
//
// Body: streaming forward fill. Loads regular (single-touch but L2 pipelines
// them); stores nontemporal (never re-read, keep L2 clean). Unroll 8 for
// outstanding-request depth.
// ---------------------------------------------------------------------------
__global__ __launch_bounds__(256) void ff_fused(
    const f4* __restrict__ data, const f4* __restrict__ mask,
    f4* __restrict__ outf, f4* __restrict__ outm) {
  const int bc = blockIdx.x;        // b*CC + c
  const int c = bc & (CC - 1);
  const int d4 = threadIdx.x;

  // ---- prologue: batched backward walk for the carry-in ----
  f4 last = {0.f, 0.f, 0.f, 0.f};   // "no valid yet" == FILL_VALUE == 0.0
  int f = (c == 0) ? 0xF : 0;       // c==0: carry is FILL, skip walk
  {
    long r = (long)c * LL;                    // exclusive upper row (within b)
    long p = (long)bc * LL * D4 + d4;         // f4 index of (b, r, d4)
    while (f != 0xF && r > 0) {
      const int nb = (r >= 4) ? 4 : (int)r;   // rows this batch
      f4 mv[4], vv[4];
#pragma unroll
      for (int k = 1; k <= 4; ++k) {          // unconditional batch loads
        if (k <= nb) {
          mv[k - 1] = mask[p - (long)k * D4];
          vv[k - 1] = data[p - (long)k * D4];
        }
      }
#pragma unroll
      for (int k = 1; k <= 4; ++k) {          // resolve newest-first
        if (k <= nb) {
          const f4 m = mv[k - 1], v = vv[k - 1];
          if (!(f & 1) && m.x > 0.f) { last.x = v.x; f |= 1; }
          if (!(f & 2) && m.y > 0.f) { last.y = v.y; f |= 2; }
          if (!(f & 4) && m.z > 0.f) { last.z = v.z; f |= 4; }
          if (!(f & 8) && m.w > 0.f) { last.w = v.w; f |= 8; }
        }
      }
      r -= nb;
      p -= (long)nb * D4;
    }
  }

  // ---- body: streaming forward fill + mask pass-through ----
  long base = (long)bc * LL * D4 + d4;
#pragma unroll 8
  for (int i = 0; i < LL; ++i, base += D4) {
    f4 m = mask[base];              // regular load (L2-pipelined)
    f4 v = data[base];
    last.x = (m.x > 0.f) ? v.x : last.x;
    last.y = (m.y > 0.f) ? v.y : last.y;
    last.z = (m.z > 0.f) ? v.z : last.z;
    last.w = (m.w > 0.f) ? v.w : last.w;
    __builtin_nontemporal_store(last, &outf[base]);
    __builtin_nontemporal_store(m, &outm[base]);
  }
}

extern "C" void kernel_launch(void* const* d_in, const int* in_sizes, int n_in,
                              void* d_out, int out_size, void* d_ws, size_t ws_size,
                              hipStream_t stream) {
  const f4* data = (const f4*)d_in[0];
  const f4* mask = (const f4*)d_in[1];
  const long N = (long)BB * TT * DD;
  f4* outf = (f4*)d_out;
  f4* outm = (f4*)((float*)d_out + N);

  ff_fused<<<BB * CC, 256, 0, stream>>>(data, mask, outf, outm);
}